// Round 3
// baseline (336.925 us; speedup 1.0000x reference)
//
#include <hip/hip_runtime.h>

// OU Euler-Maruyama: x_{i+1} = a*x_i + b_i,  a = 1 - gamma*dt (per-chain const),
// b_i = gamma*mu*dt + sigma*sqrt(dt)*eps_i.
// R3: one 256-thread BLOCK per chain (2048 blocks = 32 waves/CU, occupancy cap)
// instead of one wave per chain (R2: 8 waves/CU, latency-bound, VGPR allocator
// killed the register prefetch). Hierarchy per 8192-step tile:
//   lane: 32-step serial affine compose -> (a^32, p)
//   wave: 6-level shfl scan of affine maps
//   block: 4 wave-maps combined via LDS (1 barrier/tile, dbuf slots)
// 3 tiles/chain, sequential carry. Single noise buffer (32 VGPR) -> fits
// 8 waves/SIMD; __launch_bounds__(256,8) pins that.

#define T_STEPS 20000
#define M_PATHS 64
#define CHUNK   32                      // elements per lane per tile
#define TILE    (256 * CHUNK)           // 8192 per block-tile
#define NTILES  ((T_STEPS + TILE - 1) / TILE) // 3 (tail: 3616 = 113 lanes * 32)
#define DT      0.01f
#define SQRT_DT 0.1f

__global__ __launch_bounds__(256, 8) void ou_scan_kernel(
    const float* __restrict__ theta,
    const float* __restrict__ noise,
    float* __restrict__ out)
{
    __shared__ float2 wmap[2][4];       // [dbuf][wave] inclusive wave maps

    const int t    = threadIdx.x;
    const int wave = t >> 6;
    const int lane = t & 63;
    const int chain = blockIdx.x;       // 0..2047, = n*64 + m
    const int n     = chain / M_PATHS;

    const float gamma = theta[n * 4 + 0];
    const float mu    = theta[n * 4 + 1];
    const float sigma = theta[n * 4 + 2];
    float carry       = theta[n * 4 + 3];   // x_0

    const float a    = 1.0f - gamma * DT;
    const float gmdt = gamma * mu * DT;
    const float ssd  = sigma * SQRT_DT;
    const float a2  = a * a;
    const float a4  = a2 * a2;
    const float a8  = a4 * a4;
    const float a16 = a8 * a8;
    const float a32 = a16 * a16;

    const float* __restrict__ np_ = noise + (size_t)chain * T_STEPS;
    float* __restrict__       op_ = out   + (size_t)chain * T_STEPS;

    for (int tb = 0; tb < NTILES; ++tb) {
        const int  base = tb * TILE + t * CHUNK;
        const bool act  = (base + CHUNK <= T_STEPS);

        float4 cur[8];
        #pragma unroll
        for (int k = 0; k < 8; ++k)
            cur[k] = act ? *(const float4*)(np_ + base + 4 * k)
                         : make_float4(0.f, 0.f, 0.f, 0.f);

        // local 32-step affine compose: x_out = a^32 * x_in + p
        float p = 0.0f;
        #pragma unroll
        for (int k = 0; k < 8; ++k) {
            const float4 c = cur[k];
            p = fmaf(p, a, fmaf(ssd, c.x, gmdt));
            p = fmaf(p, a, fmaf(ssd, c.y, gmdt));
            p = fmaf(p, a, fmaf(ssd, c.z, gmdt));
            p = fmaf(p, a, fmaf(ssd, c.w, gmdt));
        }

        float A = act ? a32 : 1.0f;     // inactive lanes: identity map
        float B = act ? p   : 0.0f;

        // inclusive wave scan of affine maps (lane order = time order)
        #pragma unroll
        for (int d = 1; d < 64; d <<= 1) {
            const float pA = __shfl_up(A, d);
            const float pB = __shfl_up(B, d);
            if (lane >= d) {
                B = fmaf(A, pB, B);     // cur ∘ prev
                A = A * pA;
            }
        }

        // lane-exclusive prefix within wave
        float Aex = __shfl_up(A, 1);
        float Bex = __shfl_up(B, 1);
        if (lane == 0) { Aex = 1.0f; Bex = 0.0f; }

        // publish wave-inclusive map (lane 63)
        if (lane == 63) wmap[tb & 1][wave] = make_float2(A, B);
        __syncthreads();

        // block combine: exclusive prefix over the 4 wave maps + full map
        float EA = 1.0f, EB = 0.0f;     // running compose of waves 0..w-1
        float pEA = 1.0f, pEB = 0.0f;   // my wave's exclusive prefix
        #pragma unroll
        for (int w = 0; w < 4; ++w) {
            if (w == wave) { pEA = EA; pEB = EB; }
            const float2 m = wmap[tb & 1][w];
            EB = fmaf(m.x, EB, m.y);    // M_w ∘ E
            EA = m.x * EA;
        }

        const float xw = fmaf(pEA, carry, pEB);  // state entering my wave
        float x        = fmaf(Aex, xw, Bex);     // state entering my chunk
        carry          = fmaf(EA, carry, EB);    // state after this tile

        if (act) {
            #pragma unroll
            for (int k = 0; k < 8; ++k) {
                const float4 c = cur[k];
                float4 o;
                x = fmaf(a, x, fmaf(ssd, c.x, gmdt)); o.x = x;
                x = fmaf(a, x, fmaf(ssd, c.y, gmdt)); o.y = x;
                x = fmaf(a, x, fmaf(ssd, c.z, gmdt)); o.z = x;
                x = fmaf(a, x, fmaf(ssd, c.w, gmdt)); o.w = x;
                *(float4*)(op_ + base + 4 * k) = o;
            }
        }
        // no second barrier: dbuf slot reuse is safe — a wave reaching tile
        // tb+2's write has passed tile tb+1's barrier, which orders it after
        // every wave's tile-tb reads.
    }
}

extern "C" void kernel_launch(void* const* d_in, const int* in_sizes, int n_in,
                              void* d_out, int out_size, void* d_ws, size_t ws_size,
                              hipStream_t stream) {
    const float* theta = (const float*)d_in[0];
    const float* noise = (const float*)d_in[1];
    float* out = (float*)d_out;

    const int chains = in_sizes[1] / T_STEPS;   // 2048
    ou_scan_kernel<<<chains, 256, 0, stream>>>(theta, noise, out);
}